// Round 11
// baseline (763.866 us; speedup 1.0000x reference)
//
#include <hip/hip_runtime.h>
#include <stdint.h>

#define BB 8
#define CC 16
#define HH 96
#define WW 96
#define HID 128
#define HW (HH*WW)            // 9216
#define CHW (CC*HW)           // 147456
#define NPIX (BB*HW)          // 73728
#define STEPS 16

// ---------------- Threefry-2x32 (JAX-compatible, 20 rounds) ----------------
__host__ __device__ inline void threefry2x32(uint32_t k0, uint32_t k1,
                                             uint32_t x0, uint32_t x1,
                                             uint32_t& o0, uint32_t& o1) {
  const uint32_t ks2 = k0 ^ k1 ^ 0x1BD11BDAu;
  uint32_t v0 = x0 + k0, v1 = x1 + k1;
#define RL(v, r) (((v) << (r)) | ((v) >> (32 - (r))))
#define RND(r) { v0 += v1; v1 = RL(v1, r); v1 ^= v0; }
  RND(13) RND(15) RND(26) RND(6)   v0 += k1;  v1 += ks2 + 1u;
  RND(17) RND(29) RND(16) RND(24)  v0 += ks2; v1 += k0 + 2u;
  RND(13) RND(15) RND(26) RND(6)   v0 += k0;  v1 += k1 + 3u;
  RND(17) RND(29) RND(16) RND(24)  v0 += k1;  v1 += ks2 + 4u;
  RND(13) RND(15) RND(26) RND(6)   v0 += ks2; v1 += k0 + 5u;
#undef RND
#undef RL
  o0 = v0; o1 = v1;
}

// fire: jax.random.uniform(key_i,(B,1,H,W)) < 0.5 ; partitionable threefry:
// bits[j] = x0 ^ x1 of threefry(key_i, (0, j)); u<0.5 <=> top bit clear.
__device__ inline float fire_val(uint32_t ka, uint32_t kb, uint32_t j) {
  uint32_t r0, r1;
  threefry2x32(ka, kb, 0u, j, r0, r1);
  return ((r0 ^ r1) & 0x80000000u) ? 0.0f : 1.0f;
}

// ---------------- w2 transpose: (16,128) -> (128,16) ----------------
__global__ void transp_w2(const float* __restrict__ w2, float* __restrict__ w2t) {
  int i = threadIdx.x + blockIdx.x * blockDim.x;
  if (i < CC * HID) {
    int o = i / HID, k = i - o * HID;
    w2t[k * CC + o] = w2[i];
  }
}

// ---------------- Fused step kernel -----------------------------------------
// R11: REGISTER-RESIDENT WEIGHTS. Layer 1 runs lane=HIDDEN: each lane keeps
// its W1 row (48 floats) pinned in VGPRs for the whole block — the per-row
// wave-uniform s_load stream (the R5-R10 25us/step plateau: 13-17 quads/row
// vs 128 FMA-cyc, SGPR budget 112 -> no lookahead -> correlated lgkm stalls)
// is GONE. Features arrive as wave-uniform ds_read_b128 broadcasts (LDS pipe,
// overlaps VALU across waves). y -> LDS [128][65] (pitch 65: write lane=h and
// read lane=px both conflict-free). Layer 2 back to lane=pixel, each wave
// covers ALL 128 k for 4 channels -> no cross-wave reduction phase at all.
// Wave map: C1: w0:(h0-63,px0-31) w1:(h64-127,px0-31) w2:(h0-63,px32-63)
// w3:(h64-127,px32-63). Grid 1152 = 8 batches x 144 8x8 tiles (XCD swizzle).
__global__ __launch_bounds__(256, 3) void ca_fused(
    const float* __restrict__ src,     // x0 (step 0) or raw_{i-1}
    const float* __restrict__ plprev,  // prelife_{i-1} (ignored when step 0)
    const float* __restrict__ w1,  const float* __restrict__ b1,
    const float* __restrict__ w2t, const float* __restrict__ b2,
    float* __restrict__ rawout, float* __restrict__ plout,
    uint32_t ka, uint32_t kb, int apply_life)
{
  __shared__ float xt[CC][100];      // x_i tile, 10x10 halo'd    6.4 KiB
  __shared__ float raw3[144];        // raw ch3, 12x12            0.6 KiB
  __shared__ float life_l[100];      //                           0.4 KiB
  __shared__ float fire_lds[64];     //                           0.25 KiB
  __shared__ float p_lds[64][52];    // [px][feature], pitch 52  13.0 KiB
  __shared__ float y_lds[HID][65];   // [hidden][px], pitch 65   32.5 KiB

  const int tid  = threadIdx.x;
  const int lane = tid & 63;
  const int q    = __builtin_amdgcn_readfirstlane(tid >> 6);  // wave-uniform
  const int b    = blockIdx.x & 7;           // batch == XCD slot
  const int t    = blockIdx.x >> 3;          // tile 0..143
  const int h0   = (t / 12) * 8, w0 = (t % 12) * 8;
  const int py   = lane >> 3, px = lane & 7; // interior pixel coords
  const int h    = h0 + py, w = w0 + px;
  const int P    = b * HW + h * WW + w;      // global pixel id

  if (q == 0) fire_lds[lane] = fire_val(ka, kb, (uint32_t)P);

  // ---- A1: raw ch3 12x12 (only needed when applying life)
  if (apply_life) {
    if (tid < 144) {
      const int r = tid / 12, c = tid - r * 12;
      const int hh = h0 - 2 + r, ww = w0 - 2 + c;
      float v = 0.f;
      if (hh >= 0 && hh < HH && ww >= 0 && ww < WW)
        v = src[b * CHW + 3 * HW + hh * WW + ww];
      raw3[tid] = v;
    }
    __syncthreads();
    // ---- A2: life on the 10x10 halo region
    if (tid < 100) {
      const int r = tid / 10, c = tid - r * 10;
      float m = raw3[r * 12 + c];
      m = fmaxf(m, raw3[r * 12 + c + 1]); m = fmaxf(m, raw3[r * 12 + c + 2]);
      m = fmaxf(m, raw3[(r + 1) * 12 + c]);     m = fmaxf(m, raw3[(r + 1) * 12 + c + 1]);
      m = fmaxf(m, raw3[(r + 1) * 12 + c + 2]); m = fmaxf(m, raw3[(r + 2) * 12 + c]);
      m = fmaxf(m, raw3[(r + 2) * 12 + c + 1]); m = fmaxf(m, raw3[(r + 2) * 12 + c + 2]);
      const int hh = h0 - 1 + r, ww = w0 - 1 + c;
      float pl = 0.f;
      if (hh >= 0 && hh < HH && ww >= 0 && ww < WW)
        pl = plprev[b * HW + hh * WW + ww];
      life_l[tid] = ((m > 0.1f) && (pl > 0.1f)) ? 1.f : 0.f;
    }
    __syncthreads();
  }

  // ---- A3: build x_i tile (10x10 x 16ch), zero outside image
  for (int i = tid; i < CC * 100; i += 256) {
    const int ch = i / 100, rc = i - ch * 100;
    const int r = rc / 10, c = rc - r * 10;
    const int hh = h0 - 1 + r, ww = w0 - 1 + c;
    float v = 0.f;
    if (hh >= 0 && hh < HH && ww >= 0 && ww < WW) {
      v = src[b * CHW + ch * HW + hh * WW + ww];
      if (apply_life) {
        v *= life_l[rc];
        v = fminf(fmaxf(v, -10.f), 10.f);
      }
    }
    xt[ch][rc] = v;
  }
  __syncthreads();

  // ---- A4 (wave 0): prelife_i = 3x3 max of x_i ch3, interior pixels
  if (q == 0) {
    const int ctr0 = py * 10 + px;
    float m = xt[3][ctr0];
    m = fmaxf(m, xt[3][ctr0 + 1]);  m = fmaxf(m, xt[3][ctr0 + 2]);
    m = fmaxf(m, xt[3][ctr0 + 10]); m = fmaxf(m, xt[3][ctr0 + 11]);
    m = fmaxf(m, xt[3][ctr0 + 12]); m = fmaxf(m, xt[3][ctr0 + 20]);
    m = fmaxf(m, xt[3][ctr0 + 21]); m = fmaxf(m, xt[3][ctr0 + 22]);
    plout[P] = m;
  }

  // ---- B: perception -> p_lds[px][f] (wave q: channels q,q+4,q+8,q+12)
  const int ctr = (1 + py) * 10 + (1 + px);
#pragma unroll
  for (int cc = 0; cc < 4; ++cc) {
    const int c = q + cc * 4;                 // wave-uniform
    const float* xc = &xt[c][0];
    const float v00 = xc[ctr - 11], v01 = xc[ctr - 10], v02 = xc[ctr - 9];
    const float v10 = xc[ctr - 1],  v11 = xc[ctr],      v12 = xc[ctr + 1];
    const float v20 = xc[ctr + 9],  v21 = xc[ctr + 10], v22 = xc[ctr + 11];
    p_lds[lane][c]          = v11;
    p_lds[lane][CC + c]     = ((v02 - v00) + 2.f * (v12 - v10) + (v22 - v20)) * 0.125f;
    p_lds[lane][2 * CC + c] = ((v20 - v00) + 2.f * (v21 - v01) + (v22 - v02)) * 0.125f;
  }

  // ---- C1 weight load (overlaps perception): lane = hidden row
  const int hrow = (q & 1) * 64 + lane;
  float w1r[48];
  {
    const float4* wg = reinterpret_cast<const float4*>(w1 + hrow * 48);
#pragma unroll
    for (int i = 0; i < 12; ++i) {
      const float4 v = wg[i];
      w1r[4 * i] = v.x; w1r[4 * i + 1] = v.y; w1r[4 * i + 2] = v.z; w1r[4 * i + 3] = v.w;
    }
  }
#pragma unroll
  for (int f = 0; f < 48; ++f) asm volatile("" : "+v"(w1r[f]));  // pin in VGPRs
  const float bias1 = b1[hrow];             // per-lane vector load

  __syncthreads();                          // p_lds ready

  // ---- C1: y[hrow][px] for this wave's 32 pixels; weights from registers
  const int pxbase = (q >> 1) * 32;
  float* yrow = &y_lds[hrow][0];
  for (int pp = 0; pp < 32; ++pp) {
    const int ppx = pxbase + pp;
    const float4* pv4 = reinterpret_cast<const float4*>(&p_lds[ppx][0]);
    float a0 = bias1, a1 = 0.f, a2 = 0.f, a3 = 0.f;
#pragma unroll
    for (int cb = 0; cb < 12; ++cb) {
      const float4 pv = pv4[cb];            // wave-uniform LDS broadcast
      a0 = fmaf(w1r[4 * cb    ], pv.x, a0);
      a1 = fmaf(w1r[4 * cb + 1], pv.y, a1);
      a2 = fmaf(w1r[4 * cb + 2], pv.z, a2);
      a3 = fmaf(w1r[4 * cb + 3], pv.w, a3);
    }
    yrow[ppx] = fmaxf((a0 + a1) + (a2 + a3), 0.f);   // relu; conflict-free
  }
  __syncthreads();                          // y ready

  // ---- C2: lane = pixel; wave q -> channels 4q..4q+3, sum over ALL 128 k
  float u0 = 0.f, u1 = 0.f, u2 = 0.f, u3 = 0.f;
  const float4* w2q = reinterpret_cast<const float4*>(w2t) + q;  // quad (k*4+q)
#pragma unroll 4
  for (int k = 0; k < HID; ++k) {
    const float yv = y_lds[k][lane];        // (k+lane)%32: conflict-free
    const float4 wv = w2q[k * 4];           // wave-uniform -> s_load_dwordx4
    u0 = fmaf(wv.x, yv, u0);
    u1 = fmaf(wv.y, yv, u1);
    u2 = fmaf(wv.z, yv, u2);
    u3 = fmaf(wv.w, yv, u3);
  }

  // ---- epilogue: raw_i = x_i + upd*fire for channels 4q..4q+3
  const float fire = fire_lds[lane];
  const float4 bv = reinterpret_cast<const float4*>(b2)[q];
  const int c0 = q * 4;
  {
    const int gbase = b * CHW + h * WW + w;
    rawout[gbase + (c0    ) * HW] = xt[c0    ][ctr] + (u0 + bv.x) * fire;
    rawout[gbase + (c0 + 1) * HW] = xt[c0 + 1][ctr] + (u1 + bv.y) * fire;
    rawout[gbase + (c0 + 2) * HW] = xt[c0 + 2][ctr] + (u2 + bv.z) * fire;
    rawout[gbase + (c0 + 3) * HW] = xt[c0 + 3][ctr] + (u3 + bv.w) * fire;
  }
}

// ---------------- Final kernel: life mask + clip -> output -----------------
// grid 1152 = 8 batches x 144; block = 64 pixels x 4 channel quads.
__global__ __launch_bounds__(256) void ca_life(
    const float* __restrict__ prelife, const float* __restrict__ raw,
    float* __restrict__ xnext)
{
  const int lane = threadIdx.x & 63;
  const int g    = threadIdx.x >> 6;        // channel quad 0..3
  const int b    = blockIdx.x & 7;
  const int seg  = blockIdx.x >> 3;
  const int rem  = seg * 64 + lane;
  const int h = rem / WW;
  const int w = rem - h * WW;
  const int P = b * HW + rem;
  const bool hm = (h > 0), hp = (h < HH - 1), wm = (w > 0), wp = (w < WW - 1);

  float m2;
  {
    const float* xr = raw + b * CHW + 3 * HW + h * WW + w;
    m2 = xr[0];
    if (hm) {
      m2 = fmaxf(m2, xr[-WW]);
      if (wm) m2 = fmaxf(m2, xr[-WW - 1]);
      if (wp) m2 = fmaxf(m2, xr[-WW + 1]);
    }
    if (wm) m2 = fmaxf(m2, xr[-1]);
    if (wp) m2 = fmaxf(m2, xr[ 1]);
    if (hp) {
      m2 = fmaxf(m2, xr[WW]);
      if (wm) m2 = fmaxf(m2, xr[WW - 1]);
      if (wp) m2 = fmaxf(m2, xr[WW + 1]);
    }
  }
  const float life = ((prelife[P] > 0.1f) && (m2 > 0.1f)) ? 1.f : 0.f;

  const int base = b * CHW + h * WW + w;
#pragma unroll
  for (int cc = 0; cc < 4; ++cc) {
    const int c = g + cc * 4;               // wave-uniform
    float v = raw[base + c * HW] * life;
    v = fminf(fmaxf(v, -10.f), 10.f);
    xnext[base + c * HW] = v;
  }
}

// ---------------- launcher ----------------
extern "C" void kernel_launch(void* const* d_in, const int* in_sizes, int n_in,
                              void* d_out, int out_size, void* d_ws, size_t ws_size,
                              hipStream_t stream) {
  const float* x  = (const float*)d_in[0];
  const float* w1 = (const float*)d_in[1];
  const float* b1 = (const float*)d_in[2];
  const float* w2 = (const float*)d_in[3];
  const float* b2 = (const float*)d_in[4];
  float* out = (float*)d_out;

  char* ws = (char*)d_ws;
  const size_t BUF = (size_t)NPIX * CC * sizeof(float);   // 4,718,592 B
  float* rawA = (float*)(ws);
  float* rawB = (float*)(ws + BUF);
  float* w2t  = (float*)(ws + 2 * BUF);                   // 8 KiB
  float* plA  = (float*)(ws + 2 * BUF + 8192);            // NPIX floats
  float* plB  = (float*)(ws + 2 * BUF + 8192 + (size_t)NPIX * 4);

  hipLaunchKernelGGL(transp_w2, dim3(8), dim3(256), 0, stream, w2, w2t);

  for (int i = 0; i < STEPS; ++i) {
    uint32_t ka, kb;
    threefry2x32(0u, 42u, 0u, (uint32_t)i, ka, kb);       // fold_in(key(42), i)
    const float* src = (i == 0) ? x : ((i & 1) ? rawA : rawB);
    const float* plp = (i & 1) ? plA : plB;
    float* ro        = (i & 1) ? rawB : rawA;             // raw_i
    float* po        = (i & 1) ? plB : plA;               // prelife_i
    hipLaunchKernelGGL(ca_fused, dim3(NPIX / 64), dim3(256), 0, stream,
                       src, plp, w1, b1, w2t, b2, ro, po, ka, kb, (i == 0) ? 0 : 1);
  }
  // raw_15 / prelife_15 are in rawB / plB (15 is odd)
  hipLaunchKernelGGL(ca_life, dim3(NPIX / 64), dim3(256), 0, stream,
                     plB, rawB, out);
  (void)in_sizes; (void)n_in; (void)out_size; (void)ws_size;
}

// Round 12
// 416.201 us; speedup vs baseline: 1.8353x; 1.8353x over previous
//
#include <hip/hip_runtime.h>
#include <stdint.h>

#define BB 8
#define CC 16
#define HH 96
#define WW 96
#define HID 128
#define HW (HH*WW)            // 9216
#define CHW (CC*HW)           // 147456
#define NPIX (BB*HW)          // 73728
#define STEPS 16

typedef short s16x8 __attribute__((ext_vector_type(8)));   // 8 bf16 (4 VGPR)
typedef float f32x4 __attribute__((ext_vector_type(4)));   // MFMA acc

// ---------------- bf16 split helpers (RNE) ----------------
__device__ __host__ inline unsigned short bf16rne(float x) {
  union { float f; uint32_t u; } v; v.f = x;
  return (unsigned short)((v.u + 0x7fffu + ((v.u >> 16) & 1u)) >> 16);
}
__device__ __host__ inline float bf16f(unsigned short h) {
  union { uint32_t u; float f; } v; v.u = ((uint32_t)h) << 16; return v.f;
}

// ---------------- Threefry-2x32 (JAX-compatible, 20 rounds) ----------------
__host__ __device__ inline void threefry2x32(uint32_t k0, uint32_t k1,
                                             uint32_t x0, uint32_t x1,
                                             uint32_t& o0, uint32_t& o1) {
  const uint32_t ks2 = k0 ^ k1 ^ 0x1BD11BDAu;
  uint32_t v0 = x0 + k0, v1 = x1 + k1;
#define RL(v, r) (((v) << (r)) | ((v) >> (32 - (r))))
#define RND(r) { v0 += v1; v1 = RL(v1, r); v1 ^= v0; }
  RND(13) RND(15) RND(26) RND(6)   v0 += k1;  v1 += ks2 + 1u;
  RND(17) RND(29) RND(16) RND(24)  v0 += ks2; v1 += k0 + 2u;
  RND(13) RND(15) RND(26) RND(6)   v0 += k0;  v1 += k1 + 3u;
  RND(17) RND(29) RND(16) RND(24)  v0 += k1;  v1 += ks2 + 4u;
  RND(13) RND(15) RND(26) RND(6)   v0 += ks2; v1 += k0 + 5u;
#undef RND
#undef RL
  o0 = v0; o1 = v1;
}

// fire: partitionable threefry, bits = x0^x1 of cipher(key_i,(0,j)); <0.5 = top bit 0
__device__ inline float fire_val(uint32_t ka, uint32_t kb, uint32_t j) {
  uint32_t r0, r1;
  threefry2x32(ka, kb, 0u, j, r0, r1);
  return ((r0 ^ r1) & 0x80000000u) ? 0.0f : 1.0f;
}

// ---------------- prep: split weights into bf16 hi/lo fragments ------------
// w1f: [128][64] (K 48 real + col48 = b1 + zeros). w2f: [16][128].
__global__ void prep_w(const float* __restrict__ w1, const float* __restrict__ b1,
                       const float* __restrict__ w2,
                       unsigned short* __restrict__ w1fh, unsigned short* __restrict__ w1fl,
                       unsigned short* __restrict__ w2fh, unsigned short* __restrict__ w2fl) {
  int i = blockIdx.x * 256 + threadIdx.x;
  if (i < HID * 64) {
    int m = i >> 6, k = i & 63;
    float x = (k < 48) ? w1[m * 48 + k] : (k == 48 ? b1[m] : 0.f);
    unsigned short hb = bf16rne(x);
    w1fh[i] = hb; w1fl[i] = bf16rne(x - bf16f(hb));
  } else {
    int j = i - HID * 64;
    if (j < CC * HID) {
      float x = w2[j];
      unsigned short hb = bf16rne(x);
      w2fh[j] = hb; w2fl[j] = bf16rne(x - bf16f(hb));
    }
  }
}

// ---------------- Fused step kernel (MFMA) ----------------------------------
// Per block: 8x8 px tile. Staging identical to R10 (proven). Then:
// GEMM1 (MFMA 16x16x32 bf16, 4-pass split): Y[128][64] = W1f[128][K64]*Pf
//   b1 baked as K-col 48 (P col48 = 1.0). Wave q owns M-tiles {2q,2q+1}.
// relu+split Y -> LDS frag units. GEMM2: U[16][64] = W2f[16][128]*Yf, wave q
// owns N-tile q. Frag-unit LDS layout: unit(k,n) = (k>>3)*64 + ((n+(k>>3))&63),
// 16B = 8 k-contiguous bf16 -> all B-frag ds_read_b128 conflict-free.
// A-frags per-lane from global (issued at top, hidden under staging).
__global__ __launch_bounds__(256) void ca_fused(
    const float* __restrict__ src, const float* __restrict__ plprev,
    const unsigned short* __restrict__ w1fh, const unsigned short* __restrict__ w1fl,
    const unsigned short* __restrict__ w2fh, const unsigned short* __restrict__ w2fl,
    const float* __restrict__ b2,
    float* __restrict__ rawout, float* __restrict__ plout,
    uint32_t ka, uint32_t kb, int apply_life)
{
  __shared__ float xt[CC][100];      // x_i tile 10x10            6.4 KiB
  __shared__ float raw3[144];
  __shared__ float life_l[100];
  __shared__ float fire_lds[64];
  __shared__ __align__(16) unsigned char pfh[8192];   // P hi frags (8 kg x 64)
  __shared__ __align__(16) unsigned char pfl[8192];   // P lo
  __shared__ __align__(16) unsigned char yfh[16384];  // Y hi (16 kg x 64)
  __shared__ __align__(16) unsigned char yfl[16384];  // Y lo

  const int tid  = threadIdx.x;
  const int lane = tid & 63;
  const int q    = __builtin_amdgcn_readfirstlane(tid >> 6);
  const int b    = blockIdx.x & 7;           // batch == XCD slot
  const int t    = blockIdx.x >> 3;          // tile 0..143
  const int h0   = (t / 12) * 8, w0 = (t % 12) * 8;
  const int py   = lane >> 3, px = lane & 7;
  const int h    = h0 + py, w = w0 + px;
  const int P    = b * HW + h * WW + w;
  const int lm   = lane & 15, lg = lane >> 4;

  // ---- A-fragment global loads: issue NOW, consumed after 2 barriers
  s16x8 a1h[2][2], a1l[2][2];                // [m'][ks]
#pragma unroll
  for (int mp = 0; mp < 2; ++mp) {
    const int m = (2 * q + mp) * 16 + lm;
#pragma unroll
    for (int ks = 0; ks < 2; ++ks) {
      const int off = m * 64 + ks * 32 + lg * 8;
      a1h[mp][ks] = *reinterpret_cast<const s16x8*>(w1fh + off);
      a1l[mp][ks] = *reinterpret_cast<const s16x8*>(w1fl + off);
    }
  }
  s16x8 a2h[4], a2l[4];
#pragma unroll
  for (int ks = 0; ks < 4; ++ks) {
    const int off = lm * 128 + ks * 32 + lg * 8;
    a2h[ks] = *reinterpret_cast<const s16x8*>(w2fh + off);
    a2l[ks] = *reinterpret_cast<const s16x8*>(w2fl + off);
  }
  const f32x4 b2v = *reinterpret_cast<const f32x4*>(b2 + lg * 4);

  if (q == 0) fire_lds[lane] = fire_val(ka, kb, (uint32_t)P);

  // ---- staging: life from previous raw (proven R10 code)
  if (apply_life) {
    if (tid < 144) {
      const int r = tid / 12, c = tid - r * 12;
      const int hh = h0 - 2 + r, ww = w0 - 2 + c;
      float v = 0.f;
      if (hh >= 0 && hh < HH && ww >= 0 && ww < WW)
        v = src[b * CHW + 3 * HW + hh * WW + ww];
      raw3[tid] = v;
    }
    __syncthreads();
    if (tid < 100) {
      const int r = tid / 10, c = tid - r * 10;
      float m = raw3[r * 12 + c];
      m = fmaxf(m, raw3[r * 12 + c + 1]); m = fmaxf(m, raw3[r * 12 + c + 2]);
      m = fmaxf(m, raw3[(r + 1) * 12 + c]);     m = fmaxf(m, raw3[(r + 1) * 12 + c + 1]);
      m = fmaxf(m, raw3[(r + 1) * 12 + c + 2]); m = fmaxf(m, raw3[(r + 2) * 12 + c]);
      m = fmaxf(m, raw3[(r + 2) * 12 + c + 1]); m = fmaxf(m, raw3[(r + 2) * 12 + c + 2]);
      const int hh = h0 - 1 + r, ww = w0 - 1 + c;
      float pl = 0.f;
      if (hh >= 0 && hh < HH && ww >= 0 && ww < WW)
        pl = plprev[b * HW + hh * WW + ww];
      life_l[tid] = ((m > 0.1f) && (pl > 0.1f)) ? 1.f : 0.f;
    }
    __syncthreads();
  }

  for (int i = tid; i < CC * 100; i += 256) {
    const int ch = i / 100, rc = i - ch * 100;
    const int r = rc / 10, c = rc - r * 10;
    const int hh = h0 - 1 + r, ww = w0 - 1 + c;
    float v = 0.f;
    if (hh >= 0 && hh < HH && ww >= 0 && ww < WW) {
      v = src[b * CHW + ch * HW + hh * WW + ww];
      if (apply_life) {
        v *= life_l[rc];
        v = fminf(fmaxf(v, -10.f), 10.f);
      }
    }
    xt[ch][rc] = v;
  }
  __syncthreads();

  // ---- prelife (wave 0)
  if (q == 0) {
    const int c0 = py * 10 + px;
    float m = xt[3][c0];
    m = fmaxf(m, xt[3][c0 + 1]);  m = fmaxf(m, xt[3][c0 + 2]);
    m = fmaxf(m, xt[3][c0 + 10]); m = fmaxf(m, xt[3][c0 + 11]);
    m = fmaxf(m, xt[3][c0 + 12]); m = fmaxf(m, xt[3][c0 + 20]);
    m = fmaxf(m, xt[3][c0 + 21]); m = fmaxf(m, xt[3][c0 + 22]);
    plout[P] = m;
  }

  // ---- perception -> split-bf16 fragment units (n = lane)
  const int ctr = (1 + py) * 10 + (1 + px);
#define PUTP(K, X) do {                                                        \
    const int kg_ = (K) >> 3, e_ = (K) & 7;                                    \
    const int un_ = kg_ * 64 + ((lane + kg_) & 63);                            \
    const unsigned short hb_ = bf16rne(X);                                     \
    *reinterpret_cast<unsigned short*>(pfh + un_ * 16 + e_ * 2) = hb_;         \
    *reinterpret_cast<unsigned short*>(pfl + un_ * 16 + e_ * 2) =              \
        bf16rne((X) - bf16f(hb_));                                             \
  } while (0)
#pragma unroll
  for (int cc = 0; cc < 4; ++cc) {
    const int c = q + cc * 4;
    const float* xc = &xt[c][0];
    const float v00 = xc[ctr - 11], v01 = xc[ctr - 10], v02 = xc[ctr - 9];
    const float v10 = xc[ctr - 1],  v11 = xc[ctr],      v12 = xc[ctr + 1];
    const float v20 = xc[ctr + 9],  v21 = xc[ctr + 10], v22 = xc[ctr + 11];
    const float gx = ((v02 - v00) + 2.f * (v12 - v10) + (v22 - v20)) * 0.125f;
    const float gy = ((v20 - v00) + 2.f * (v21 - v01) + (v22 - v02)) * 0.125f;
    PUTP(c, v11);
    PUTP(16 + c, gx);
    PUTP(32 + c, gy);
  }
#undef PUTP
  // K padding: col48 = 1.0 (bias), 49..63 = 0
  {
    const int u6 = 6 * 64 + ((lane + 6) & 63);
    const int u7 = 7 * 64 + ((lane + 7) & 63);
    *reinterpret_cast<uint4*>(pfh + u6 * 16) = make_uint4(0x3f80u, 0u, 0u, 0u);
    *reinterpret_cast<uint4*>(pfl + u6 * 16) = make_uint4(0u, 0u, 0u, 0u);
    *reinterpret_cast<uint4*>(pfh + u7 * 16) = make_uint4(0u, 0u, 0u, 0u);
    *reinterpret_cast<uint4*>(pfl + u7 * 16) = make_uint4(0u, 0u, 0u, 0u);
  }
  __syncthreads();

  // ---- GEMM1: acc[m'][nt] += W1 * P  (4-pass split)
  f32x4 acc[2][4];
#pragma unroll
  for (int mp = 0; mp < 2; ++mp)
#pragma unroll
    for (int nt = 0; nt < 4; ++nt) acc[mp][nt] = (f32x4){0.f, 0.f, 0.f, 0.f};

#pragma unroll
  for (int nt = 0; nt < 4; ++nt) {
#pragma unroll
    for (int ks = 0; ks < 2; ++ks) {
      const int kg = ks * 4 + lg;
      const int un = kg * 64 + ((nt * 16 + lm + kg) & 63);
      const s16x8 bh = *reinterpret_cast<const s16x8*>(pfh + un * 16);
      const s16x8 bl = *reinterpret_cast<const s16x8*>(pfl + un * 16);
#pragma unroll
      for (int mp = 0; mp < 2; ++mp) {
        acc[mp][nt] = __builtin_amdgcn_mfma_f32_16x16x32_bf16(a1l[mp][ks], bl, acc[mp][nt], 0, 0, 0);
        acc[mp][nt] = __builtin_amdgcn_mfma_f32_16x16x32_bf16(a1l[mp][ks], bh, acc[mp][nt], 0, 0, 0);
        acc[mp][nt] = __builtin_amdgcn_mfma_f32_16x16x32_bf16(a1h[mp][ks], bl, acc[mp][nt], 0, 0, 0);
        acc[mp][nt] = __builtin_amdgcn_mfma_f32_16x16x32_bf16(a1h[mp][ks], bh, acc[mp][nt], 0, 0, 0);
      }
    }
  }

  // ---- Y = relu(acc), split to bf16 hi/lo, write frag units
#pragma unroll
  for (int mp = 0; mp < 2; ++mp) {
    const int k0 = (2 * q + mp) * 16 + lg * 4;   // 4 consecutive k (rows)
    const int kg = k0 >> 3, e0 = k0 & 7;         // e0 in {0,4}
#pragma unroll
    for (int nt = 0; nt < 4; ++nt) {
      const int un = kg * 64 + ((nt * 16 + lm + kg) & 63);
      unsigned int hwv[2], lwv[2];
#pragma unroll
      for (int pr = 0; pr < 2; ++pr) {
        const float ya = fmaxf(acc[mp][nt][2 * pr], 0.f);
        const float yb = fmaxf(acc[mp][nt][2 * pr + 1], 0.f);
        const unsigned short ha = bf16rne(ya), hb2 = bf16rne(yb);
        const unsigned short la = bf16rne(ya - bf16f(ha));
        const unsigned short lb = bf16rne(yb - bf16f(hb2));
        hwv[pr] = (unsigned int)ha | ((unsigned int)hb2 << 16);
        lwv[pr] = (unsigned int)la | ((unsigned int)lb << 16);
      }
      *reinterpret_cast<uint2*>(yfh + un * 16 + e0 * 2) = make_uint2(hwv[0], hwv[1]);
      *reinterpret_cast<uint2*>(yfl + un * 16 + e0 * 2) = make_uint2(lwv[0], lwv[1]);
    }
  }
  __syncthreads();

  // ---- GEMM2: U[16][16px] for N-tile q (4-pass split over K=128)
  f32x4 acc2 = (f32x4){0.f, 0.f, 0.f, 0.f};
#pragma unroll
  for (int ks = 0; ks < 4; ++ks) {
    const int kg = ks * 4 + lg;
    const int un = kg * 64 + ((q * 16 + lm + kg) & 63);
    const s16x8 bh = *reinterpret_cast<const s16x8*>(yfh + un * 16);
    const s16x8 bl = *reinterpret_cast<const s16x8*>(yfl + un * 16);
    acc2 = __builtin_amdgcn_mfma_f32_16x16x32_bf16(a2l[ks], bl, acc2, 0, 0, 0);
    acc2 = __builtin_amdgcn_mfma_f32_16x16x32_bf16(a2l[ks], bh, acc2, 0, 0, 0);
    acc2 = __builtin_amdgcn_mfma_f32_16x16x32_bf16(a2h[ks], bl, acc2, 0, 0, 0);
    acc2 = __builtin_amdgcn_mfma_f32_16x16x32_bf16(a2h[ks], bh, acc2, 0, 0, 0);
  }

  // ---- epilogue: raw = x + (U + b2) * fire ; C/D: row c=(lg)*4+r, col px
  const int opx = q * 16 + lm;
  const float fire = fire_lds[opx];
  const int opy = opx >> 3, owx = opx & 7;
  const int octr = (1 + opy) * 10 + (1 + owx);
  const int gb = b * CHW + (h0 + opy) * WW + (w0 + owx);
#pragma unroll
  for (int r = 0; r < 4; ++r) {
    const int c = lg * 4 + r;
    rawout[gb + c * HW] = xt[c][octr] + (acc2[r] + b2v[r]) * fire;
  }
}

// ---------------- Final kernel: life mask + clip -> output -----------------
__global__ __launch_bounds__(256) void ca_life(
    const float* __restrict__ prelife, const float* __restrict__ raw,
    float* __restrict__ xnext)
{
  const int lane = threadIdx.x & 63;
  const int g    = threadIdx.x >> 6;
  const int b    = blockIdx.x & 7;
  const int seg  = blockIdx.x >> 3;
  const int rem  = seg * 64 + lane;
  const int h = rem / WW;
  const int w = rem - h * WW;
  const int P = b * HW + rem;
  const bool hm = (h > 0), hp = (h < HH - 1), wm = (w > 0), wp = (w < WW - 1);

  float m2;
  {
    const float* xr = raw + b * CHW + 3 * HW + h * WW + w;
    m2 = xr[0];
    if (hm) {
      m2 = fmaxf(m2, xr[-WW]);
      if (wm) m2 = fmaxf(m2, xr[-WW - 1]);
      if (wp) m2 = fmaxf(m2, xr[-WW + 1]);
    }
    if (wm) m2 = fmaxf(m2, xr[-1]);
    if (wp) m2 = fmaxf(m2, xr[ 1]);
    if (hp) {
      m2 = fmaxf(m2, xr[WW]);
      if (wm) m2 = fmaxf(m2, xr[WW - 1]);
      if (wp) m2 = fmaxf(m2, xr[WW + 1]);
    }
  }
  const float life = ((prelife[P] > 0.1f) && (m2 > 0.1f)) ? 1.f : 0.f;

  const int base = b * CHW + h * WW + w;
#pragma unroll
  for (int cc = 0; cc < 4; ++cc) {
    const int c = g + cc * 4;
    float v = raw[base + c * HW] * life;
    v = fminf(fmaxf(v, -10.f), 10.f);
    xnext[base + c * HW] = v;
  }
}

// ---------------- launcher ----------------
extern "C" void kernel_launch(void* const* d_in, const int* in_sizes, int n_in,
                              void* d_out, int out_size, void* d_ws, size_t ws_size,
                              hipStream_t stream) {
  const float* x  = (const float*)d_in[0];
  const float* w1 = (const float*)d_in[1];
  const float* b1 = (const float*)d_in[2];
  const float* w2 = (const float*)d_in[3];
  const float* b2 = (const float*)d_in[4];
  float* out = (float*)d_out;

  char* ws = (char*)d_ws;
  const size_t BUF = (size_t)NPIX * CC * sizeof(float);   // 4,718,592 B
  float* rawA = (float*)(ws);
  float* rawB = (float*)(ws + BUF);
  float* plA  = (float*)(ws + 2 * BUF);
  float* plB  = (float*)(ws + 2 * BUF + (size_t)NPIX * 4);
  unsigned short* w1fh = (unsigned short*)(ws + 2 * BUF + 2 * (size_t)NPIX * 4);
  unsigned short* w1fl = w1fh + HID * 64;
  unsigned short* w2fh = w1fl + HID * 64;
  unsigned short* w2fl = w2fh + CC * HID;

  hipLaunchKernelGGL(prep_w, dim3(40), dim3(256), 0, stream,
                     w1, b1, w2, w1fh, w1fl, w2fh, w2fl);

  for (int i = 0; i < STEPS; ++i) {
    uint32_t ka, kb;
    threefry2x32(0u, 42u, 0u, (uint32_t)i, ka, kb);       // fold_in(key(42), i)
    const float* src = (i == 0) ? x : ((i & 1) ? rawA : rawB);
    const float* plp = (i & 1) ? plA : plB;
    float* ro        = (i & 1) ? rawB : rawA;             // raw_i
    float* po        = (i & 1) ? plB : plA;               // prelife_i
    hipLaunchKernelGGL(ca_fused, dim3(NPIX / 64), dim3(256), 0, stream,
                       src, plp, w1fh, w1fl, w2fh, w2fl, b2, ro, po,
                       ka, kb, (i == 0) ? 0 : 1);
  }
  // raw_15 / prelife_15 are in rawB / plB (15 is odd)
  hipLaunchKernelGGL(ca_life, dim3(NPIX / 64), dim3(256), 0, stream,
                     plB, rawB, out);
  (void)in_sizes; (void)n_in; (void)out_size; (void)ws_size;
}

// Round 13
// 230.376 us; speedup vs baseline: 3.3157x; 1.8066x over previous
//
#include <hip/hip_runtime.h>
#include <stdint.h>

#define BB 8
#define CC 16
#define HH 96
#define WW 96
#define HID 128
#define HW (HH*WW)            // 9216
#define CHW (CC*HW)           // 147456
#define NPIX (BB*HW)          // 73728
#define STEPS 16

typedef short s16x8 __attribute__((ext_vector_type(8)));   // 8 bf16 (4 VGPR)
typedef float f32x4 __attribute__((ext_vector_type(4)));   // MFMA acc

// ---------------- bf16 split helpers (RNE) ----------------
__device__ __host__ inline unsigned short bf16rne(float x) {
  union { float f; uint32_t u; } v; v.f = x;
  return (unsigned short)((v.u + 0x7fffu + ((v.u >> 16) & 1u)) >> 16);
}
__device__ __host__ inline float bf16f(unsigned short h) {
  union { uint32_t u; float f; } v; v.u = ((uint32_t)h) << 16; return v.f;
}

// ---------------- Threefry-2x32 (JAX-compatible, 20 rounds) ----------------
__host__ __device__ inline void threefry2x32(uint32_t k0, uint32_t k1,
                                             uint32_t x0, uint32_t x1,
                                             uint32_t& o0, uint32_t& o1) {
  const uint32_t ks2 = k0 ^ k1 ^ 0x1BD11BDAu;
  uint32_t v0 = x0 + k0, v1 = x1 + k1;
#define RL(v, r) (((v) << (r)) | ((v) >> (32 - (r))))
#define RND(r) { v0 += v1; v1 = RL(v1, r); v1 ^= v0; }
  RND(13) RND(15) RND(26) RND(6)   v0 += k1;  v1 += ks2 + 1u;
  RND(17) RND(29) RND(16) RND(24)  v0 += ks2; v1 += k0 + 2u;
  RND(13) RND(15) RND(26) RND(6)   v0 += k0;  v1 += k1 + 3u;
  RND(17) RND(29) RND(16) RND(24)  v0 += k1;  v1 += ks2 + 4u;
  RND(13) RND(15) RND(26) RND(6)   v0 += ks2; v1 += k0 + 5u;
#undef RND
#undef RL
  o0 = v0; o1 = v1;
}

// fire: partitionable threefry, bits = x0^x1 of cipher(key_i,(0,j)); <0.5 = top bit 0
__device__ inline float fire_val(uint32_t ka, uint32_t kb, uint32_t j) {
  uint32_t r0, r1;
  threefry2x32(ka, kb, 0u, j, r0, r1);
  return ((r0 ^ r1) & 0x80000000u) ? 0.0f : 1.0f;
}

// ---------------- prep: split + PRE-PERMUTE weights into fragment order -----
// w1 ext: [128][64] (K48 real, col48 = b1, rest 0). Frag addr for (q,mp,ks,lane):
//   dst_unit = ((q*2+mp)*2+ks)*64 + lane, lane = lg*16+lm, m=(2q+mp)*16+lm,
//   k = (ks*4+lg)*8+e.  -> ca_fused loads are fully coalesced dwordx4.
__global__ void prep_w(const float* __restrict__ w1, const float* __restrict__ b1,
                       const float* __restrict__ w2,
                       unsigned short* __restrict__ w1fh, unsigned short* __restrict__ w1fl,
                       unsigned short* __restrict__ w2fh, unsigned short* __restrict__ w2fl) {
  int i = blockIdx.x * 256 + threadIdx.x;
  if (i < HID * 64) {
    int m = i >> 6, k = i & 63;
    float x = (k < 48) ? w1[m * 48 + k] : (k == 48 ? b1[m] : 0.f);
    int q = m >> 5, mp = (m >> 4) & 1, lm = m & 15;
    int kg = k >> 3, e = k & 7, ks = kg >> 2, lg = kg & 3;
    int dst = ((((q * 2 + mp) * 2 + ks) * 64) + lg * 16 + lm) * 8 + e;
    unsigned short hb = bf16rne(x);
    w1fh[dst] = hb; w1fl[dst] = bf16rne(x - bf16f(hb));
  } else if (i < HID * 64 + CC * HID) {
    int j = i - HID * 64;
    int m = j >> 7, k = j & 127;
    float x = w2[m * 128 + k];
    int kg = k >> 3, e = k & 7, ks = kg >> 2, lg = kg & 3;
    int dst = ((ks * 64) + lg * 16 + m) * 8 + e;
    unsigned short hb = bf16rne(x);
    w2fh[dst] = hb; w2fl[dst] = bf16rne(x - bf16f(hb));
  }
}

// ---------------- Fused step kernel (MFMA, slim scaffold) --------------------
// LDS overlay: pf[0:16K] / xt[16K:22.4K] / raw3,life[22.4K:23.8K] live early;
// yf[0:32K] overlays them after GEMM1 (barrier-protected). fire separate.
// Staging split T14-style: ALL global loads issued at top; raw3->life barrier
// chain hides x-tile latency. Weights arrive as coalesced pre-permuted frags.
// 3-pass split MFMA (drop lo*lo, ~4e-4 abs contribution).
__global__ __launch_bounds__(256, 3) void ca_fused(
    const float* __restrict__ src, const float* __restrict__ plprev,
    const unsigned short* __restrict__ w1fh, const unsigned short* __restrict__ w1fl,
    const unsigned short* __restrict__ w2fh, const unsigned short* __restrict__ w2fl,
    const float* __restrict__ b2,
    float* __restrict__ rawout, float* __restrict__ plout,
    uint32_t ka, uint32_t kb, int apply_life)
{
  __shared__ __align__(16) unsigned char smem[33024];
  unsigned char* pfh   = smem;                  // 8192
  unsigned char* pfl   = smem + 8192;           // 8192
  float* xt            = (float*)(smem + 16384); // [16][100] = 6400 B
  float* raw3          = (float*)(smem + 22784); // 576 B
  float* life_l        = (float*)(smem + 23360); // 400 B
  unsigned char* yfh   = smem;                  // 16384 (overlay pf)
  unsigned char* yfl   = smem + 16384;          // 16384 (overlay xt/raw3/life)
  float* fire_lds      = (float*)(smem + 32768); // 256 B

  const int tid  = threadIdx.x;
  const int lane = tid & 63;
  const int q    = __builtin_amdgcn_readfirstlane(tid >> 6);
  const int b    = blockIdx.x & 7;           // batch == XCD slot
  const int t    = blockIdx.x >> 3;          // tile 0..143
  const int h0   = (t / 12) * 8, w0 = (t % 12) * 8;
  const int py   = lane >> 3, px = lane & 7;
  const int h    = h0 + py, w = w0 + px;
  const int P    = b * HW + h * WW + w;
  const int lm   = lane & 15, lg = lane >> 4;

  // ---- A-fragments: fully coalesced loads from pre-permuted arrays
  s16x8 a1h[2][2], a1l[2][2];
#pragma unroll
  for (int mp = 0; mp < 2; ++mp)
#pragma unroll
    for (int ks = 0; ks < 2; ++ks) {
      const int off = ((((q * 2 + mp) * 2 + ks) * 64) + lane) * 8;
      a1h[mp][ks] = *reinterpret_cast<const s16x8*>(w1fh + off);
      a1l[mp][ks] = *reinterpret_cast<const s16x8*>(w1fl + off);
    }
  s16x8 a2h[4], a2l[4];
#pragma unroll
  for (int ks = 0; ks < 4; ++ks) {
    const int off = ((ks * 64) + lane) * 8;
    a2h[ks] = *reinterpret_cast<const s16x8*>(w2fh + off);
    a2l[ks] = *reinterpret_cast<const s16x8*>(w2fl + off);
  }
  const f32x4 b2v = reinterpret_cast<const f32x4*>(b2)[lg];

  // ---- issue ALL staging loads now (latency hidden by barrier chain below)
  float r3v = 0.f;
  if (apply_life && tid < 144) {
    const int r = tid / 12, c = tid - r * 12;
    const int hh = h0 - 2 + r, ww = w0 - 2 + c;
    if (hh >= 0 && hh < HH && ww >= 0 && ww < WW)
      r3v = src[b * CHW + 3 * HW + hh * WW + ww];
  }
  float plv = 0.f;
  if (apply_life && tid < 100) {
    const int r = tid / 10, c = tid - r * 10;
    const int hh = h0 - 1 + r, ww = w0 - 1 + c;
    if (hh >= 0 && hh < HH && ww >= 0 && ww < WW)
      plv = plprev[b * HW + hh * WW + ww];
  }
  float xreg[7];
#pragma unroll
  for (int ii = 0; ii < 7; ++ii) {
    xreg[ii] = 0.f;
    const int idx = tid + ii * 256;
    if (idx < CC * 100) {
      const int ch = idx / 100, rc = idx - ch * 100;
      const int r = rc / 10, c = rc - r * 10;
      const int hh = h0 - 1 + r, ww = w0 - 1 + c;
      if (hh >= 0 && hh < HH && ww >= 0 && ww < WW)
        xreg[ii] = src[b * CHW + ch * HW + hh * WW + ww];
    }
  }

  if (q == 0) fire_lds[lane] = fire_val(ka, kb, (uint32_t)P);  // overlaps loads

  // ---- life chain
  if (apply_life) {
    if (tid < 144) raw3[tid] = r3v;
    __syncthreads();
    if (tid < 100) {
      const int r = tid / 10, c = tid - r * 10;
      float m = raw3[r * 12 + c];
      m = fmaxf(m, raw3[r * 12 + c + 1]); m = fmaxf(m, raw3[r * 12 + c + 2]);
      m = fmaxf(m, raw3[(r + 1) * 12 + c]);     m = fmaxf(m, raw3[(r + 1) * 12 + c + 1]);
      m = fmaxf(m, raw3[(r + 1) * 12 + c + 2]); m = fmaxf(m, raw3[(r + 2) * 12 + c]);
      m = fmaxf(m, raw3[(r + 2) * 12 + c + 1]); m = fmaxf(m, raw3[(r + 2) * 12 + c + 2]);
      life_l[tid] = ((m > 0.1f) && (plv > 0.1f)) ? 1.f : 0.f;
    }
    __syncthreads();
  }

  // ---- build x tile from prefetched registers
#pragma unroll
  for (int ii = 0; ii < 7; ++ii) {
    const int idx = tid + ii * 256;
    if (idx < CC * 100) {
      const int ch = idx / 100, rc = idx - ch * 100;
      float v = xreg[ii];
      if (apply_life) {
        v *= life_l[rc];
        v = fminf(fmaxf(v, -10.f), 10.f);
      }
      xt[ch * 100 + rc] = v;
    }
  }
  __syncthreads();

  // ---- prelife (wave 0)
  if (q == 0) {
    const int c0 = py * 10 + px;
    const float* x3 = xt + 3 * 100;
    float m = x3[c0];
    m = fmaxf(m, x3[c0 + 1]);  m = fmaxf(m, x3[c0 + 2]);
    m = fmaxf(m, x3[c0 + 10]); m = fmaxf(m, x3[c0 + 11]);
    m = fmaxf(m, x3[c0 + 12]); m = fmaxf(m, x3[c0 + 20]);
    m = fmaxf(m, x3[c0 + 21]); m = fmaxf(m, x3[c0 + 22]);
    plout[P] = m;
  }

  // ---- perception -> split-bf16 fragment units (n = lane)
  const int ctr = (1 + py) * 10 + (1 + px);
#define PUTP(K, X) do {                                                        \
    const int kg_ = (K) >> 3, e_ = (K) & 7;                                    \
    const int un_ = kg_ * 64 + ((lane + kg_) & 63);                            \
    const unsigned short hb_ = bf16rne(X);                                     \
    *reinterpret_cast<unsigned short*>(pfh + un_ * 16 + e_ * 2) = hb_;         \
    *reinterpret_cast<unsigned short*>(pfl + un_ * 16 + e_ * 2) =              \
        bf16rne((X) - bf16f(hb_));                                             \
  } while (0)
#pragma unroll
  for (int cc = 0; cc < 4; ++cc) {
    const int c = q + cc * 4;
    const float* xc = xt + c * 100;
    const float v00 = xc[ctr - 11], v01 = xc[ctr - 10], v02 = xc[ctr - 9];
    const float v10 = xc[ctr - 1],  v11 = xc[ctr],      v12 = xc[ctr + 1];
    const float v20 = xc[ctr + 9],  v21 = xc[ctr + 10], v22 = xc[ctr + 11];
    const float gx = ((v02 - v00) + 2.f * (v12 - v10) + (v22 - v20)) * 0.125f;
    const float gy = ((v20 - v00) + 2.f * (v21 - v01) + (v22 - v02)) * 0.125f;
    PUTP(c, v11);
    PUTP(16 + c, gx);
    PUTP(32 + c, gy);
  }
#undef PUTP
  {  // K padding: col48 = 1.0 (bias), 49..63 = 0
    const int u6 = 6 * 64 + ((lane + 6) & 63);
    const int u7 = 7 * 64 + ((lane + 7) & 63);
    *reinterpret_cast<uint4*>(pfh + u6 * 16) = make_uint4(0x3f80u, 0u, 0u, 0u);
    *reinterpret_cast<uint4*>(pfl + u6 * 16) = make_uint4(0u, 0u, 0u, 0u);
    *reinterpret_cast<uint4*>(pfh + u7 * 16) = make_uint4(0u, 0u, 0u, 0u);
    *reinterpret_cast<uint4*>(pfl + u7 * 16) = make_uint4(0u, 0u, 0u, 0u);
  }
  __syncthreads();                 // pf ready; xt final

  // ---- epilogue center values -> registers (xt dies before yf overlay)
  const int opx = q * 16 + lm;
  const int opy = opx >> 3, owx = opx & 7;
  const int octr = (1 + opy) * 10 + (1 + owx);
  float xcv[4];
#pragma unroll
  for (int r = 0; r < 4; ++r) xcv[r] = xt[(lg * 4 + r) * 100 + octr];

  // ---- GEMM1: acc += W1*P, 3-pass split
  f32x4 acc[2][4];
#pragma unroll
  for (int mp = 0; mp < 2; ++mp)
#pragma unroll
    for (int nt = 0; nt < 4; ++nt) acc[mp][nt] = (f32x4){0.f, 0.f, 0.f, 0.f};

#pragma unroll
  for (int nt = 0; nt < 4; ++nt) {
#pragma unroll
    for (int ks = 0; ks < 2; ++ks) {
      const int kg = ks * 4 + lg;
      const int un = kg * 64 + ((nt * 16 + lm + kg) & 63);
      const s16x8 bh = *reinterpret_cast<const s16x8*>(pfh + un * 16);
      const s16x8 bl = *reinterpret_cast<const s16x8*>(pfl + un * 16);
#pragma unroll
      for (int mp = 0; mp < 2; ++mp) {
        acc[mp][nt] = __builtin_amdgcn_mfma_f32_16x16x32_bf16(a1l[mp][ks], bh, acc[mp][nt], 0, 0, 0);
        acc[mp][nt] = __builtin_amdgcn_mfma_f32_16x16x32_bf16(a1h[mp][ks], bl, acc[mp][nt], 0, 0, 0);
        acc[mp][nt] = __builtin_amdgcn_mfma_f32_16x16x32_bf16(a1h[mp][ks], bh, acc[mp][nt], 0, 0, 0);
      }
    }
  }
  __syncthreads();                 // all pf reads done -> safe to overlay yf

  // ---- Y = relu(acc) split to bf16 hi/lo frag units
#pragma unroll
  for (int mp = 0; mp < 2; ++mp) {
    const int k0 = (2 * q + mp) * 16 + lg * 4;
    const int kg = k0 >> 3, e0 = k0 & 7;
#pragma unroll
    for (int nt = 0; nt < 4; ++nt) {
      const int un = kg * 64 + ((nt * 16 + lm + kg) & 63);
      unsigned int hwv[2], lwv[2];
#pragma unroll
      for (int pr = 0; pr < 2; ++pr) {
        const float ya = fmaxf(acc[mp][nt][2 * pr], 0.f);
        const float yb = fmaxf(acc[mp][nt][2 * pr + 1], 0.f);
        const unsigned short ha = bf16rne(ya), hb2 = bf16rne(yb);
        const unsigned short la = bf16rne(ya - bf16f(ha));
        const unsigned short lb = bf16rne(yb - bf16f(hb2));
        hwv[pr] = (unsigned int)ha | ((unsigned int)hb2 << 16);
        lwv[pr] = (unsigned int)la | ((unsigned int)lb << 16);
      }
      *reinterpret_cast<uint2*>(yfh + un * 16 + e0 * 2) = make_uint2(hwv[0], hwv[1]);
      *reinterpret_cast<uint2*>(yfl + un * 16 + e0 * 2) = make_uint2(lwv[0], lwv[1]);
    }
  }
  __syncthreads();                 // yf ready

  // ---- GEMM2: U[16][16px] for N-tile q, 3-pass split over K=128
  f32x4 acc2 = (f32x4){0.f, 0.f, 0.f, 0.f};
#pragma unroll
  for (int ks = 0; ks < 4; ++ks) {
    const int kg = ks * 4 + lg;
    const int un = kg * 64 + ((q * 16 + lm + kg) & 63);
    const s16x8 bh = *reinterpret_cast<const s16x8*>(yfh + un * 16);
    const s16x8 bl = *reinterpret_cast<const s16x8*>(yfl + un * 16);
    acc2 = __builtin_amdgcn_mfma_f32_16x16x32_bf16(a2l[ks], bh, acc2, 0, 0, 0);
    acc2 = __builtin_amdgcn_mfma_f32_16x16x32_bf16(a2h[ks], bl, acc2, 0, 0, 0);
    acc2 = __builtin_amdgcn_mfma_f32_16x16x32_bf16(a2h[ks], bh, acc2, 0, 0, 0);
  }

  // ---- epilogue: raw = x + (U + b2) * fire
  const float fire = fire_lds[opx];
  const int gb = b * CHW + (h0 + opy) * WW + (w0 + owx);
#pragma unroll
  for (int r = 0; r < 4; ++r) {
    const int c = lg * 4 + r;
    rawout[gb + c * HW] = xcv[r] + (acc2[r] + b2v[r]) * fire;
  }
}

// ---------------- Final kernel: life mask + clip -> output -----------------
__global__ __launch_bounds__(256) void ca_life(
    const float* __restrict__ prelife, const float* __restrict__ raw,
    float* __restrict__ xnext)
{
  const int lane = threadIdx.x & 63;
  const int g    = threadIdx.x >> 6;
  const int b    = blockIdx.x & 7;
  const int seg  = blockIdx.x >> 3;
  const int rem  = seg * 64 + lane;
  const int h = rem / WW;
  const int w = rem - h * WW;
  const int P = b * HW + rem;
  const bool hm = (h > 0), hp = (h < HH - 1), wm = (w > 0), wp = (w < WW - 1);

  float m2;
  {
    const float* xr = raw + b * CHW + 3 * HW + h * WW + w;
    m2 = xr[0];
    if (hm) {
      m2 = fmaxf(m2, xr[-WW]);
      if (wm) m2 = fmaxf(m2, xr[-WW - 1]);
      if (wp) m2 = fmaxf(m2, xr[-WW + 1]);
    }
    if (wm) m2 = fmaxf(m2, xr[-1]);
    if (wp) m2 = fmaxf(m2, xr[ 1]);
    if (hp) {
      m2 = fmaxf(m2, xr[WW]);
      if (wm) m2 = fmaxf(m2, xr[WW - 1]);
      if (wp) m2 = fmaxf(m2, xr[WW + 1]);
    }
  }
  const float life = ((prelife[P] > 0.1f) && (m2 > 0.1f)) ? 1.f : 0.f;

  const int base = b * CHW + h * WW + w;
#pragma unroll
  for (int cc = 0; cc < 4; ++cc) {
    const int c = g + cc * 4;
    float v = raw[base + c * HW] * life;
    v = fminf(fmaxf(v, -10.f), 10.f);
    xnext[base + c * HW] = v;
  }
}

// ---------------- launcher ----------------
extern "C" void kernel_launch(void* const* d_in, const int* in_sizes, int n_in,
                              void* d_out, int out_size, void* d_ws, size_t ws_size,
                              hipStream_t stream) {
  const float* x  = (const float*)d_in[0];
  const float* w1 = (const float*)d_in[1];
  const float* b1 = (const float*)d_in[2];
  const float* w2 = (const float*)d_in[3];
  const float* b2 = (const float*)d_in[4];
  float* out = (float*)d_out;

  char* ws = (char*)d_ws;
  const size_t BUF = (size_t)NPIX * CC * sizeof(float);   // 4,718,592 B
  float* rawA = (float*)(ws);
  float* rawB = (float*)(ws + BUF);
  float* plA  = (float*)(ws + 2 * BUF);
  float* plB  = (float*)(ws + 2 * BUF + (size_t)NPIX * 4);
  unsigned short* w1fh = (unsigned short*)(ws + 2 * BUF + 2 * (size_t)NPIX * 4);
  unsigned short* w1fl = w1fh + HID * 64;
  unsigned short* w2fh = w1fl + HID * 64;
  unsigned short* w2fl = w2fh + CC * HID;

  hipLaunchKernelGGL(prep_w, dim3(40), dim3(256), 0, stream,
                     w1, b1, w2, w1fh, w1fl, w2fh, w2fl);

  for (int i = 0; i < STEPS; ++i) {
    uint32_t ka, kb;
    threefry2x32(0u, 42u, 0u, (uint32_t)i, ka, kb);       // fold_in(key(42), i)
    const float* src = (i == 0) ? x : ((i & 1) ? rawA : rawB);
    const float* plp = (i & 1) ? plA : plB;
    float* ro        = (i & 1) ? rawB : rawA;             // raw_i
    float* po        = (i & 1) ? plB : plA;               // prelife_i
    hipLaunchKernelGGL(ca_fused, dim3(NPIX / 64), dim3(256), 0, stream,
                       src, plp, w1fh, w1fl, w2fh, w2fl, b2, ro, po,
                       ka, kb, (i == 0) ? 0 : 1);
  }
  // raw_15 / prelife_15 are in rawB / plB (15 is odd)
  hipLaunchKernelGGL(ca_life, dim3(NPIX / 64), dim3(256), 0, stream,
                     plB, rawB, out);
  (void)in_sizes; (void)n_in; (void)out_size; (void)ws_size;
}

// Round 15
// 227.450 us; speedup vs baseline: 3.3584x; 1.0129x over previous
//
#include <hip/hip_runtime.h>
#include <stdint.h>

#define BB 8
#define CC 16
#define HH 96
#define WW 96
#define HID 128
#define HW (HH*WW)            // 9216
#define CHW (CC*HW)           // 147456
#define NPIX (BB*HW)          // 73728
#define STEPS 16

typedef short s16x8 __attribute__((ext_vector_type(8)));   // 8 bf16 (4 VGPR)
typedef float f32x4 __attribute__((ext_vector_type(4)));   // MFMA acc

// ---------------- bf16 split helpers (RNE) ----------------
__device__ __host__ inline unsigned short bf16rne(float x) {
  union { float f; uint32_t u; } v; v.f = x;
  return (unsigned short)((v.u + 0x7fffu + ((v.u >> 16) & 1u)) >> 16);
}
__device__ __host__ inline float bf16f(unsigned short h) {
  union { uint32_t u; float f; } v; v.u = ((uint32_t)h) << 16; return v.f;
}

// ---------------- Threefry-2x32 (JAX-compatible, 20 rounds) ----------------
__host__ __device__ inline void threefry2x32(uint32_t k0, uint32_t k1,
                                             uint32_t x0, uint32_t x1,
                                             uint32_t& o0, uint32_t& o1) {
  const uint32_t ks2 = k0 ^ k1 ^ 0x1BD11BDAu;
  uint32_t v0 = x0 + k0, v1 = x1 + k1;
#define RL(v, r) (((v) << (r)) | ((v) >> (32 - (r))))
#define RND(r) { v0 += v1; v1 = RL(v1, r); v1 ^= v0; }
  RND(13) RND(15) RND(26) RND(6)   v0 += k1;  v1 += ks2 + 1u;
  RND(17) RND(29) RND(16) RND(24)  v0 += ks2; v1 += k0 + 2u;
  RND(13) RND(15) RND(26) RND(6)   v0 += k0;  v1 += k1 + 3u;
  RND(17) RND(29) RND(16) RND(24)  v0 += k1;  v1 += ks2 + 4u;
  RND(13) RND(15) RND(26) RND(6)   v0 += ks2; v1 += k0 + 5u;
#undef RND
#undef RL
  o0 = v0; o1 = v1;
}

// fire: partitionable threefry, bits = x0^x1 of cipher(key_i,(0,j)); <0.5 = top bit 0
__device__ inline float fire_val(uint32_t ka, uint32_t kb, uint32_t j) {
  uint32_t r0, r1;
  threefry2x32(ka, kb, 0u, j, r0, r1);
  return ((r0 ^ r1) & 0x80000000u) ? 0.0f : 1.0f;
}

// ---------------- prep: split + PRE-PERMUTE weights into fragment order -----
__global__ void prep_w(const float* __restrict__ w1, const float* __restrict__ b1,
                       const float* __restrict__ w2,
                       unsigned short* __restrict__ w1fh, unsigned short* __restrict__ w1fl,
                       unsigned short* __restrict__ w2fh, unsigned short* __restrict__ w2fl) {
  int i = blockIdx.x * 256 + threadIdx.x;
  if (i < HID * 64) {
    int m = i >> 6, k = i & 63;
    float x = (k < 48) ? w1[m * 48 + k] : (k == 48 ? b1[m] : 0.f);
    int q = m >> 5, mp = (m >> 4) & 1, lm = m & 15;
    int kg = k >> 3, e = k & 7, ks = kg >> 2, lg = kg & 3;
    int dst = ((((q * 2 + mp) * 2 + ks) * 64) + lg * 16 + lm) * 8 + e;
    unsigned short hb = bf16rne(x);
    w1fh[dst] = hb; w1fl[dst] = bf16rne(x - bf16f(hb));
  } else if (i < HID * 64 + CC * HID) {
    int j = i - HID * 64;
    int m = j >> 7, k = j & 127;
    float x = w2[m * 128 + k];
    int kg = k >> 3, e = k & 7, ks = kg >> 2, lg = kg & 3;
    int dst = ((ks * 64) + lg * 16 + m) * 8 + e;
    unsigned short hb = bf16rne(x);
    w2fh[dst] = hb; w2fl[dst] = bf16rne(x - bf16f(hb));
  }
}

// ---------------- Fused step kernel (MFMA; R13 numerics + deferred a2) ------
// Numerics = R13 exactly (3-pass GEMM1, 3-pass GEMM2 incl. y_lo — R14 proved
// dropping w2h*y_lo flips life bits: threshold at 0.1 amplifies ~0.02 error
// to ~6). Structural: a2 frags loaded AFTER yf barrier (-32 VGPR live range),
// launch_bounds(256,4) -> 4 blocks/CU (LDS 33KB allows 4; VGPR peak ~100<128).
__global__ __launch_bounds__(256, 4) void ca_fused(
    const float* __restrict__ src, const float* __restrict__ plprev,
    const unsigned short* __restrict__ w1fh, const unsigned short* __restrict__ w1fl,
    const unsigned short* __restrict__ w2fh, const unsigned short* __restrict__ w2fl,
    const float* __restrict__ b2,
    float* __restrict__ rawout, float* __restrict__ plout,
    uint32_t ka, uint32_t kb, int apply_life)
{
  __shared__ __align__(16) unsigned char smem[33024];
  unsigned char* pfh   = smem;                  // 8192
  unsigned char* pfl   = smem + 8192;           // 8192
  float* xt            = (float*)(smem + 16384); // [16][100] = 6400 B
  float* raw3          = (float*)(smem + 22784); // 576 B
  float* life_l        = (float*)(smem + 23360); // 400 B
  unsigned char* yfh   = smem;                  // 16384 (overlay pf)
  unsigned char* yfl   = smem + 16384;          // 16384 (overlay xt/raw3/life)
  float* fire_lds      = (float*)(smem + 32768); // 256 B

  const int tid  = threadIdx.x;
  const int lane = tid & 63;
  const int q    = __builtin_amdgcn_readfirstlane(tid >> 6);
  const int b    = blockIdx.x & 7;           // batch == XCD slot
  const int t    = blockIdx.x >> 3;          // tile 0..143
  const int h0   = (t / 12) * 8, w0 = (t % 12) * 8;
  const int py   = lane >> 3, px = lane & 7;
  const int h    = h0 + py, w = w0 + px;
  const int P    = b * HW + h * WW + w;
  const int lm   = lane & 15, lg = lane >> 4;

  // ---- A1-fragments: fully coalesced loads from pre-permuted arrays
  s16x8 a1h[2][2], a1l[2][2];
#pragma unroll
  for (int mp = 0; mp < 2; ++mp)
#pragma unroll
    for (int ks = 0; ks < 2; ++ks) {
      const int off = ((((q * 2 + mp) * 2 + ks) * 64) + lane) * 8;
      a1h[mp][ks] = *reinterpret_cast<const s16x8*>(w1fh + off);
      a1l[mp][ks] = *reinterpret_cast<const s16x8*>(w1fl + off);
    }
  const f32x4 b2v = reinterpret_cast<const f32x4*>(b2)[lg];

  // ---- issue ALL staging loads now (latency hidden by barrier chain below)
  float r3v = 0.f;
  if (apply_life && tid < 144) {
    const int r = tid / 12, c = tid - r * 12;
    const int hh = h0 - 2 + r, ww = w0 - 2 + c;
    if (hh >= 0 && hh < HH && ww >= 0 && ww < WW)
      r3v = src[b * CHW + 3 * HW + hh * WW + ww];
  }
  float plv = 0.f;
  if (apply_life && tid < 100) {
    const int r = tid / 10, c = tid - r * 10;
    const int hh = h0 - 1 + r, ww = w0 - 1 + c;
    if (hh >= 0 && hh < HH && ww >= 0 && ww < WW)
      plv = plprev[b * HW + hh * WW + ww];
  }
  float xreg[7];
#pragma unroll
  for (int ii = 0; ii < 7; ++ii) {
    xreg[ii] = 0.f;
    const int idx = tid + ii * 256;
    if (idx < CC * 100) {
      const int ch = idx / 100, rc = idx - ch * 100;
      const int r = rc / 10, c = rc - r * 10;
      const int hh = h0 - 1 + r, ww = w0 - 1 + c;
      if (hh >= 0 && hh < HH && ww >= 0 && ww < WW)
        xreg[ii] = src[b * CHW + ch * HW + hh * WW + ww];
    }
  }

  if (q == 0) fire_lds[lane] = fire_val(ka, kb, (uint32_t)P);  // overlaps loads

  // ---- life chain
  if (apply_life) {
    if (tid < 144) raw3[tid] = r3v;
    __syncthreads();
    if (tid < 100) {
      const int r = tid / 10, c = tid - r * 10;
      float m = raw3[r * 12 + c];
      m = fmaxf(m, raw3[r * 12 + c + 1]); m = fmaxf(m, raw3[r * 12 + c + 2]);
      m = fmaxf(m, raw3[(r + 1) * 12 + c]);     m = fmaxf(m, raw3[(r + 1) * 12 + c + 1]);
      m = fmaxf(m, raw3[(r + 1) * 12 + c + 2]); m = fmaxf(m, raw3[(r + 2) * 12 + c]);
      m = fmaxf(m, raw3[(r + 2) * 12 + c + 1]); m = fmaxf(m, raw3[(r + 2) * 12 + c + 2]);
      life_l[tid] = ((m > 0.1f) && (plv > 0.1f)) ? 1.f : 0.f;
    }
    __syncthreads();
  }

  // ---- build x tile from prefetched registers
#pragma unroll
  for (int ii = 0; ii < 7; ++ii) {
    const int idx = tid + ii * 256;
    if (idx < CC * 100) {
      const int ch = idx / 100, rc = idx - ch * 100;
      float v = xreg[ii];
      if (apply_life) {
        v *= life_l[rc];
        v = fminf(fmaxf(v, -10.f), 10.f);
      }
      xt[ch * 100 + rc] = v;
    }
  }
  __syncthreads();

  // ---- prelife (wave 0)
  if (q == 0) {
    const int c0 = py * 10 + px;
    const float* x3 = xt + 3 * 100;
    float m = x3[c0];
    m = fmaxf(m, x3[c0 + 1]);  m = fmaxf(m, x3[c0 + 2]);
    m = fmaxf(m, x3[c0 + 10]); m = fmaxf(m, x3[c0 + 11]);
    m = fmaxf(m, x3[c0 + 12]); m = fmaxf(m, x3[c0 + 20]);
    m = fmaxf(m, x3[c0 + 21]); m = fmaxf(m, x3[c0 + 22]);
    plout[P] = m;
  }

  // ---- perception -> split-bf16 fragment units (n = lane)
  const int ctr = (1 + py) * 10 + (1 + px);
#define PUTP(K, X) do {                                                        \
    const int kg_ = (K) >> 3, e_ = (K) & 7;                                    \
    const int un_ = kg_ * 64 + ((lane + kg_) & 63);                            \
    const unsigned short hb_ = bf16rne(X);                                     \
    *reinterpret_cast<unsigned short*>(pfh + un_ * 16 + e_ * 2) = hb_;         \
    *reinterpret_cast<unsigned short*>(pfl + un_ * 16 + e_ * 2) =              \
        bf16rne((X) - bf16f(hb_));                                             \
  } while (0)
#pragma unroll
  for (int cc = 0; cc < 4; ++cc) {
    const int c = q + cc * 4;
    const float* xc = xt + c * 100;
    const float v00 = xc[ctr - 11], v01 = xc[ctr - 10], v02 = xc[ctr - 9];
    const float v10 = xc[ctr - 1],  v11 = xc[ctr],      v12 = xc[ctr + 1];
    const float v20 = xc[ctr + 9],  v21 = xc[ctr + 10], v22 = xc[ctr + 11];
    const float gx = ((v02 - v00) + 2.f * (v12 - v10) + (v22 - v20)) * 0.125f;
    const float gy = ((v20 - v00) + 2.f * (v21 - v01) + (v22 - v02)) * 0.125f;
    PUTP(c, v11);
    PUTP(16 + c, gx);
    PUTP(32 + c, gy);
  }
#undef PUTP
  {  // K padding: col48 = 1.0 (bias), 49..63 = 0
    const int u6 = 6 * 64 + ((lane + 6) & 63);
    const int u7 = 7 * 64 + ((lane + 7) & 63);
    *reinterpret_cast<uint4*>(pfh + u6 * 16) = make_uint4(0x3f80u, 0u, 0u, 0u);
    *reinterpret_cast<uint4*>(pfl + u6 * 16) = make_uint4(0u, 0u, 0u, 0u);
    *reinterpret_cast<uint4*>(pfh + u7 * 16) = make_uint4(0u, 0u, 0u, 0u);
    *reinterpret_cast<uint4*>(pfl + u7 * 16) = make_uint4(0u, 0u, 0u, 0u);
  }
  __syncthreads();                 // pf ready; xt final

  // ---- epilogue center values -> registers (xt dies before yf overlay)
  const int opx = q * 16 + lm;
  const int opy = opx >> 3, owx = opx & 7;
  const int octr = (1 + opy) * 10 + (1 + owx);
  float xcv[4];
#pragma unroll
  for (int r = 0; r < 4; ++r) xcv[r] = xt[(lg * 4 + r) * 100 + octr];

  // ---- GEMM1: acc += W1*P, 3-pass split
  f32x4 acc[2][4];
#pragma unroll
  for (int mp = 0; mp < 2; ++mp)
#pragma unroll
    for (int nt = 0; nt < 4; ++nt) acc[mp][nt] = (f32x4){0.f, 0.f, 0.f, 0.f};

#pragma unroll
  for (int nt = 0; nt < 4; ++nt) {
#pragma unroll
    for (int ks = 0; ks < 2; ++ks) {
      const int kg = ks * 4 + lg;
      const int un = kg * 64 + ((nt * 16 + lm + kg) & 63);
      const s16x8 bh = *reinterpret_cast<const s16x8*>(pfh + un * 16);
      const s16x8 bl = *reinterpret_cast<const s16x8*>(pfl + un * 16);
#pragma unroll
      for (int mp = 0; mp < 2; ++mp) {
        acc[mp][nt] = __builtin_amdgcn_mfma_f32_16x16x32_bf16(a1l[mp][ks], bh, acc[mp][nt], 0, 0, 0);
        acc[mp][nt] = __builtin_amdgcn_mfma_f32_16x16x32_bf16(a1h[mp][ks], bl, acc[mp][nt], 0, 0, 0);
        acc[mp][nt] = __builtin_amdgcn_mfma_f32_16x16x32_bf16(a1h[mp][ks], bh, acc[mp][nt], 0, 0, 0);
      }
    }
  }
  __syncthreads();                 // all pf reads done -> safe to overlay yf

  // ---- Y = relu(acc) split to bf16 hi/lo frag units
#pragma unroll
  for (int mp = 0; mp < 2; ++mp) {
    const int k0 = (2 * q + mp) * 16 + lg * 4;
    const int kg = k0 >> 3, e0 = k0 & 7;
#pragma unroll
    for (int nt = 0; nt < 4; ++nt) {
      const int un = kg * 64 + ((nt * 16 + lm + kg) & 63);
      unsigned int hwv[2], lwv[2];
#pragma unroll
      for (int pr = 0; pr < 2; ++pr) {
        const float ya = fmaxf(acc[mp][nt][2 * pr], 0.f);
        const float yb = fmaxf(acc[mp][nt][2 * pr + 1], 0.f);
        const unsigned short ha = bf16rne(ya), hb2 = bf16rne(yb);
        const unsigned short la = bf16rne(ya - bf16f(ha));
        const unsigned short lb = bf16rne(yb - bf16f(hb2));
        hwv[pr] = (unsigned int)ha | ((unsigned int)hb2 << 16);
        lwv[pr] = (unsigned int)la | ((unsigned int)lb << 16);
      }
      *reinterpret_cast<uint2*>(yfh + un * 16 + e0 * 2) = make_uint2(hwv[0], hwv[1]);
      *reinterpret_cast<uint2*>(yfl + un * 16 + e0 * 2) = make_uint2(lwv[0], lwv[1]);
    }
  }
  __syncthreads();                 // yf ready

  // ---- GEMM2: U[16][16px] for N-tile q, 3-pass split; a2 frags loaded HERE
  f32x4 acc2 = (f32x4){0.f, 0.f, 0.f, 0.f};
#pragma unroll
  for (int ks = 0; ks < 4; ++ks) {
    const int woff = ((ks * 64) + lane) * 8;
    const s16x8 a2l = *reinterpret_cast<const s16x8*>(w2fl + woff);  // L2-hot
    const s16x8 a2h = *reinterpret_cast<const s16x8*>(w2fh + woff);
    const int kg = ks * 4 + lg;
    const int un = kg * 64 + ((q * 16 + lm + kg) & 63);
    const s16x8 bh = *reinterpret_cast<const s16x8*>(yfh + un * 16);
    const s16x8 bl = *reinterpret_cast<const s16x8*>(yfl + un * 16);
    acc2 = __builtin_amdgcn_mfma_f32_16x16x32_bf16(a2l, bh, acc2, 0, 0, 0);
    acc2 = __builtin_amdgcn_mfma_f32_16x16x32_bf16(a2h, bl, acc2, 0, 0, 0);
    acc2 = __builtin_amdgcn_mfma_f32_16x16x32_bf16(a2h, bh, acc2, 0, 0, 0);
  }

  // ---- epilogue: raw = x + (U + b2) * fire
  const float fire = fire_lds[opx];
  const int gb = b * CHW + (h0 + opy) * WW + (w0 + owx);
#pragma unroll
  for (int r = 0; r < 4; ++r) {
    const int c = lg * 4 + r;
    rawout[gb + c * HW] = xcv[r] + (acc2[r] + b2v[r]) * fire;
  }
}

// ---------------- Final kernel: life mask + clip -> output -----------------
__global__ __launch_bounds__(256) void ca_life(
    const float* __restrict__ prelife, const float* __restrict__ raw,
    float* __restrict__ xnext)
{
  const int lane = threadIdx.x & 63;
  const int g    = threadIdx.x >> 6;
  const int b    = blockIdx.x & 7;
  const int seg  = blockIdx.x >> 3;
  const int rem  = seg * 64 + lane;
  const int h = rem / WW;
  const int w = rem - h * WW;
  const int P = b * HW + rem;
  const bool hm = (h > 0), hp = (h < HH - 1), wm = (w > 0), wp = (w < WW - 1);

  float m2;
  {
    const float* xr = raw + b * CHW + 3 * HW + h * WW + w;
    m2 = xr[0];
    if (hm) {
      m2 = fmaxf(m2, xr[-WW]);
      if (wm) m2 = fmaxf(m2, xr[-WW - 1]);
      if (wp) m2 = fmaxf(m2, xr[-WW + 1]);
    }
    if (wm) m2 = fmaxf(m2, xr[-1]);
    if (wp) m2 = fmaxf(m2, xr[ 1]);
    if (hp) {
      m2 = fmaxf(m2, xr[WW]);
      if (wm) m2 = fmaxf(m2, xr[WW - 1]);
      if (wp) m2 = fmaxf(m2, xr[WW + 1]);
    }
  }
  const float life = ((prelife[P] > 0.1f) && (m2 > 0.1f)) ? 1.f : 0.f;

  const int base = b * CHW + h * WW + w;
#pragma unroll
  for (int cc = 0; cc < 4; ++cc) {
    const int c = g + cc * 4;
    float v = raw[base + c * HW] * life;
    v = fminf(fmaxf(v, -10.f), 10.f);
    xnext[base + c * HW] = v;
  }
}

// ---------------- launcher ----------------
extern "C" void kernel_launch(void* const* d_in, const int* in_sizes, int n_in,
                              void* d_out, int out_size, void* d_ws, size_t ws_size,
                              hipStream_t stream) {
  const float* x  = (const float*)d_in[0];
  const float* w1 = (const float*)d_in[1];
  const float* b1 = (const float*)d_in[2];
  const float* w2 = (const float*)d_in[3];
  const float* b2 = (const float*)d_in[4];
  float* out = (float*)d_out;

  char* ws = (char*)d_ws;
  const size_t BUF = (size_t)NPIX * CC * sizeof(float);   // 4,718,592 B
  float* rawA = (float*)(ws);
  float* rawB = (float*)(ws + BUF);
  float* plA  = (float*)(ws + 2 * BUF);
  float* plB  = (float*)(ws + 2 * BUF + (size_t)NPIX * 4);
  unsigned short* w1fh = (unsigned short*)(ws + 2 * BUF + 2 * (size_t)NPIX * 4);
  unsigned short* w1fl = w1fh + HID * 64;
  unsigned short* w2fh = w1fl + HID * 64;
  unsigned short* w2fl = w2fh + CC * HID;

  hipLaunchKernelGGL(prep_w, dim3(40), dim3(256), 0, stream,
                     w1, b1, w2, w1fh, w1fl, w2fh, w2fl);

  for (int i = 0; i < STEPS; ++i) {
    uint32_t ka, kb;
    threefry2x32(0u, 42u, 0u, (uint32_t)i, ka, kb);       // fold_in(key(42), i)
    const float* src = (i == 0) ? x : ((i & 1) ? rawA : rawB);
    const float* plp = (i & 1) ? plA : plB;
    float* ro        = (i & 1) ? rawB : rawA;             // raw_i
    float* po        = (i & 1) ? plB : plA;               // prelife_i
    hipLaunchKernelGGL(ca_fused, dim3(NPIX / 64), dim3(256), 0, stream,
                       src, plp, w1fh, w1fl, w2fh, w2fl, b2, ro, po,
                       ka, kb, (i == 0) ? 0 : 1);
  }
  // raw_15 / prelife_15 are in rawB / plB (15 is odd)
  hipLaunchKernelGGL(ca_life, dim3(NPIX / 64), dim3(256), 0, stream,
                     plB, rawB, out);
  (void)in_sizes; (void)n_in; (void)out_size; (void)ws_size;
}